// Round 3
// baseline (851.085 us; speedup 1.0000x reference)
//
#include <hip/hip_runtime.h>
#include <hip/hip_bf16.h>
#include <math.h>

#define N0 4096
#define NM1 8192

// workspace float offsets
#define OFF_U    0
#define OFF_XL1  65536
#define OFF_XL2  131072
#define OFF_UL1  196608
#define OFF_UL2  262144
#define OFF_INV  327680
#define OFF_PX   331776      // 8 * 65536
#define OFF_PU   856064      // 8 * 65536
#define OFF_PRS  1380352     // 8 * 4096
#define OFF_BAR  1413120     // int region from here
#define BAR_INTS 3728        // 7*33*16 + 16

// ---------------------------------------------------------------------------
// two-level grid barrier: 32 groups of 32 blocks -> root -> release flag.
// Residency guaranteed: launch_bounds(256,4) caps VGPR<=128 (4 waves/SIMD),
// LDS 32KB*4 = 128 <= 160KB, grid = 4 blocks/CU * 256 CU exactly.
// ---------------------------------------------------------------------------
__device__ __forceinline__ void grid_barrier(int* bar, int bi) {
  __syncthreads();
  if (threadIdx.x == 0) {
    const int gid = blockIdx.x >> 5;
    int* grp  = bar + (bi * 33 + gid) * 16;
    int* root = bar + (bi * 33 + 32) * 16;
    int* rel  = bar + 231 * 16;
    if (__hip_atomic_fetch_add(grp, 1, __ATOMIC_ACQ_REL, __HIP_MEMORY_SCOPE_AGENT) == 31) {
      if (__hip_atomic_fetch_add(root, 1, __ATOMIC_ACQ_REL, __HIP_MEMORY_SCOPE_AGENT) == 31) {
        __hip_atomic_store(rel, bi + 1, __ATOMIC_RELEASE, __HIP_MEMORY_SCOPE_AGENT);
      }
    }
    while (__hip_atomic_load(rel, __ATOMIC_ACQUIRE, __HIP_MEMORY_SCOPE_AGENT) < bi + 1) {
      __builtin_amdgcn_s_sleep(2);
    }
  }
  __syncthreads();
}

// butterfly reduce-scatter: 2*NV values -> NV, exchanging with lane^d
template<int NV>
__device__ __forceinline__ void red_scatter(float* v, const int d, const int lane) {
  const bool up = (lane & d) != 0;
  #pragma unroll
  for (int i = 0; i < NV; ++i) {
    float send = up ? v[i] : v[i + NV];
    float recv = __shfl_xor(send, d);
    float keep = up ? v[i + NV] : v[i];
    v[i] = keep + recv;
  }
}

// ---------------------------------------------------------------------------
// P0: pP[s] = B1[rows, m-range(s)] @ x1.  8 rows/wave, q=lane>>4 (1 of 4
// col-blocks), ml=lane&15. 1024 blocks = 128 rg x 8 s. chunks 2 x 512 m.
// ---------------------------------------------------------------------------
__device__ __forceinline__ void b1_phase(const float* __restrict__ A,
                                         const float* __restrict__ X,
                                         float* __restrict__ pP,
                                         float4* Bs) {
  const int tid  = threadIdx.x;
  const int wv   = tid >> 6;
  const int lane = tid & 63;
  const int q    = lane >> 4;
  const int ml   = lane & 15;
  const int s    = blockIdx.x & 7;
  const int rg   = blockIdx.x >> 3;
  const int row0 = rg * 32 + wv * 8;
  const int mbase = s * 1024;

  float acc[32];
  #pragma unroll
  for (int i = 0; i < 32; ++i) acc[i] = 0.0f;

  const int jj = tid & 3;
  const int mt = tid >> 2;    // 0..63

  #pragma unroll 1
  for (int ch = 0; ch < 2; ++ch) {
    const int mb = mbase + ch * 512;
    __syncthreads();
    #pragma unroll
    for (int k = 0; k < 8; ++k) {
      const int m = mt + 64 * k;
      Bs[(m * 4 + jj) ^ ((m >> 2) & 7)] =
          *(const float4*)(X + (size_t)(mb + m) * 16 + jj * 4);
    }
    __syncthreads();
    #pragma unroll 2
    for (int it = 0; it < 8; ++it) {
      const int mloc = it * 64 + ml * 4;
      float a_[8][4];
      #pragma unroll
      for (int r = 0; r < 8; ++r) {
        const float4 t4 = *(const float4*)(A + (size_t)(row0 + r) * NM1 + mb + mloc);
        a_[r][0] = t4.x; a_[r][1] = t4.y; a_[r][2] = t4.z; a_[r][3] = t4.w;
      }
      #pragma unroll
      for (int v = 0; v < 4; ++v) {
        const int mm = mloc + v;
        const float4 b0 = Bs[(mm * 4 + q) ^ ((mm >> 2) & 7)];
        #pragma unroll
        for (int r = 0; r < 8; ++r) {
          const float av = a_[r][v];
          acc[r*4+0] += av * b0.x;  acc[r*4+1] += av * b0.y;
          acc[r*4+2] += av * b0.z;  acc[r*4+3] += av * b0.w;
        }
      }
    }
  }

  // reduce across 16 m-lanes: 32 vals -> 2 per lane
  red_scatter<16>(acc, 1, lane);
  red_scatter<8>(acc, 2, lane);
  red_scatter<4>(acc, 4, lane);
  red_scatter<2>(acc, 8, lane);

  const int r  = 4 * (ml & 1) + 2 * ((ml >> 1) & 1) + ((ml >> 2) & 1);
  const int c0 = 2 * ((ml >> 3) & 1);
  *(float2*)(pP + (size_t)(s * 65536) + (row0 + r) * 16 + q * 4 + c0) =
      make_float2(acc[0], acc[1]);
}

// ---------------------------------------------------------------------------
// P2/P4/P6: pX/pU[s] = L0[rows, m-range(s)] @ {cx, cu} (+rowsum when RS).
// 8 rows/wave, q=lane>>3 (1 of 8 col-blocks: 0-3 x-chain, 4-7 u-chain),
// ml=lane&7. 1024 blocks = 128 rg x 8 s. chunks 2 x 256 m.
// ---------------------------------------------------------------------------
template<bool RS>
__device__ __forceinline__ void cheb_phase(const float* __restrict__ A,
                                           const float* __restrict__ cx,
                                           const float* __restrict__ cu,
                                           float* __restrict__ pX,
                                           float* __restrict__ pU,
                                           float* __restrict__ pRS,
                                           float4* Bs) {
  const int tid  = threadIdx.x;
  const int wv   = tid >> 6;
  const int lane = tid & 63;
  const int q    = lane >> 3;
  const int ml   = lane & 7;
  const int s    = blockIdx.x & 7;
  const int rg   = blockIdx.x >> 3;
  const int row0 = rg * 32 + wv * 8;
  const int mbase = s * 512;

  float acc[32];
  #pragma unroll
  for (int i = 0; i < 32; ++i) acc[i] = 0.0f;
  float rs[8] = {};

  const int jj = tid & 7;
  const int mt = tid >> 3;     // 0..31
  const float* sbase = (jj < 4) ? cx : cu;
  const int joff = (jj & 3) * 4;

  #pragma unroll 1
  for (int ch = 0; ch < 2; ++ch) {
    const int mb = mbase + ch * 256;
    __syncthreads();
    #pragma unroll
    for (int k = 0; k < 8; ++k) {
      const int m = mt + 32 * k;
      Bs[(m * 8 + jj) ^ ((m >> 2) & 7)] =
          *(const float4*)(sbase + (size_t)(mb + m) * 16 + joff);
    }
    __syncthreads();
    #pragma unroll 2
    for (int it = 0; it < 8; ++it) {
      const int mloc = it * 32 + ml * 4;
      float a_[8][4];
      #pragma unroll
      for (int r = 0; r < 8; ++r) {
        const float4 t4 = *(const float4*)(A + (size_t)(row0 + r) * N0 + mb + mloc);
        a_[r][0] = t4.x; a_[r][1] = t4.y; a_[r][2] = t4.z; a_[r][3] = t4.w;
      }
      #pragma unroll
      for (int v = 0; v < 4; ++v) {
        const int mm = mloc + v;
        const float4 b0 = Bs[(mm * 8 + q) ^ ((mm >> 2) & 7)];
        #pragma unroll
        for (int r = 0; r < 8; ++r) {
          const float av = a_[r][v];
          acc[r*4+0] += av * b0.x;  acc[r*4+1] += av * b0.y;
          acc[r*4+2] += av * b0.z;  acc[r*4+3] += av * b0.w;
          if constexpr (RS) rs[r] += av;
        }
      }
    }
  }

  // reduce across 8 m-lanes: 32 vals -> 4 per lane
  red_scatter<16>(acc, 1, lane);
  red_scatter<8>(acc, 2, lane);
  red_scatter<4>(acc, 4, lane);

  const int r = 4 * (ml & 1) + 2 * ((ml >> 1) & 1) + ((ml >> 2) & 1);
  float* base = (q >> 2) ? pU : pX;
  *(float4*)(base + (size_t)(s * 65536) + (row0 + r) * 16 + (q & 3) * 4) =
      make_float4(acc[0], acc[1], acc[2], acc[3]);

  if constexpr (RS) {
    // rowsum: sum across all 8 ml lanes while scattering r (q duplicates)
    red_scatter<4>(rs, 1, lane);
    red_scatter<2>(rs, 2, lane);
    red_scatter<1>(rs, 4, lane);
    if (q == 0) pRS[s * N0 + row0 + r] = rs[0];
  }
}

// P1: u = sum_s pP[s]
__device__ __forceinline__ void finalize_phase(const float* __restrict__ pP,
                                               float* __restrict__ u) {
  const int idx = blockIdx.x * 256 + threadIdx.x;
  float a = 0.0f;
  #pragma unroll
  for (int s2 = 0; s2 < 8; ++s2) a += pP[s2 * 65536 + idx];
  u[idx] = a;
}

// P3/P5: sum partials, aggr_norm. FIRST also computes+stores inv from pRS.
template<bool FIRST>
__device__ __forceinline__ void norm_phase(const float* __restrict__ pX,
                                           const float* __restrict__ pU,
                                           const float* __restrict__ pRS,
                                           float* __restrict__ inv,
                                           float* __restrict__ ox,
                                           float* __restrict__ ou) {
  const int idx = blockIdx.x * 256 + threadIdx.x;
  const int row = idx >> 4;
  float iv;
  if constexpr (FIRST) {
    float rsv = 0.0f;
    #pragma unroll
    for (int s2 = 0; s2 < 8; ++s2) rsv += pRS[s2 * N0 + row];
    iv = 1.0f / rsv;
    if (!isfinite(iv)) iv = 0.0f;
    if ((idx & 15) == 0) inv[row] = iv;
  } else {
    iv = inv[row];
  }
  float xv = 0.0f, uv = 0.0f;
  #pragma unroll
  for (int s2 = 0; s2 < 8; ++s2) { xv += pX[s2*65536 + idx]; uv += pU[s2*65536 + idx]; }
  xv *= iv; uv *= iv;
  ox[idx] = isfinite(xv) ? xv : 0.0f;
  ou[idx] = isfinite(uv) ? uv : 0.0f;
}

// P7: y0[n,o] = sum_{i,k} xall[n,i,k]*W[i,o,k]; step-3 norm fused from partials
__device__ __forceinline__ void einsum_phase(const float* __restrict__ x0,
                                             const float* __restrict__ xl1,
                                             const float* __restrict__ xl2,
                                             const float* __restrict__ u,
                                             const float* __restrict__ ul1,
                                             const float* __restrict__ ul2,
                                             const float* __restrict__ pX,
                                             const float* __restrict__ pU,
                                             const float* __restrict__ inv,
                                             const float* __restrict__ W,
                                             float* __restrict__ y,
                                             float* smem) {
  float* Wl = smem;              // 2048
  float* xs = smem + 2048;       // 2048: [r][k][i]
  const int t = threadIdx.x;
  const int row0 = blockIdx.x * 16;
  #pragma unroll
  for (int k = 0; k < 8; ++k) Wl[t + 256 * k] = W[t + 256 * k];
  const int r = t >> 4;
  const int i = t & 15;
  const int g = (row0 + r) * 16 + i;
  const float iv = inv[row0 + r];
  float x3 = 0.0f, u3 = 0.0f;
  #pragma unroll
  for (int s2 = 0; s2 < 8; ++s2) { x3 += pX[s2*65536 + g]; u3 += pU[s2*65536 + g]; }
  x3 *= iv; u3 *= iv;
  if (!isfinite(x3)) x3 = 0.0f;
  if (!isfinite(u3)) u3 = 0.0f;
  xs[r*128 + 0*16 + i] = x0[g];
  xs[r*128 + 1*16 + i] = xl1[g];
  xs[r*128 + 2*16 + i] = xl2[g];
  xs[r*128 + 3*16 + i] = x3;
  xs[r*128 + 4*16 + i] = u[g];
  xs[r*128 + 5*16 + i] = ul1[g];
  xs[r*128 + 6*16 + i] = ul2[g];
  xs[r*128 + 7*16 + i] = u3;
  __syncthreads();
  const int o = t & 15;
  float a = 0.0f;
  #pragma unroll
  for (int ii = 0; ii < 16; ++ii) {
    #pragma unroll
    for (int k = 0; k < 8; ++k)
      a += xs[r*128 + k*16 + ii] * Wl[(ii*16 + o)*8 + k];
  }
  y[(row0 + r) * 16 + o] = a;
}

__global__ void init_bar_kernel(int* bar) {
  for (int i = threadIdx.x; i < BAR_INTS; i += 256) bar[i] = 0;
}

// ---------------------------------------------------------------------------
__global__ __launch_bounds__(256, 4)
void mega_kernel(const float* __restrict__ x0, const float* __restrict__ x1,
                 const float* __restrict__ L0, const float* __restrict__ B1,
                 const float* __restrict__ W0, float* __restrict__ ws,
                 int* __restrict__ bar, float* __restrict__ y) {
  __shared__ float4 Bs[2048];    // 32 KiB, reused by all phases
  float* u   = ws + OFF_U;
  float* xl1 = ws + OFF_XL1;
  float* xl2 = ws + OFF_XL2;
  float* ul1 = ws + OFF_UL1;
  float* ul2 = ws + OFF_UL2;
  float* inv = ws + OFF_INV;
  float* pX  = ws + OFF_PX;
  float* pU  = ws + OFF_PU;
  float* pRS = ws + OFF_PRS;

  // P0: b1 partials (into pX region)
  b1_phase(B1, x1, pX, Bs);
  grid_barrier(bar, 0);
  // P1: u = sum partials
  if (blockIdx.x < 256) finalize_phase(pX, u);
  grid_barrier(bar, 1);
  // P2: cheb step 1 (+rowsum)
  cheb_phase<true>(L0, x0, u, pX, pU, pRS, Bs);
  grid_barrier(bar, 2);
  // P3: inv + normalize -> xl1, ul1
  if (blockIdx.x < 256) norm_phase<true>(pX, pU, pRS, inv, xl1, ul1);
  grid_barrier(bar, 3);
  // P4: cheb step 2
  cheb_phase<false>(L0, xl1, ul1, pX, pU, pRS, Bs);
  grid_barrier(bar, 4);
  // P5: normalize -> xl2, ul2
  if (blockIdx.x < 256) norm_phase<false>(pX, pU, pRS, inv, xl2, ul2);
  grid_barrier(bar, 5);
  // P6: cheb step 3
  cheb_phase<false>(L0, xl2, ul2, pX, pU, pRS, Bs);
  grid_barrier(bar, 6);
  // P7: einsum with step-3 norm fused
  if (blockIdx.x < 256)
    einsum_phase(x0, xl1, xl2, u, ul1, ul2, pX, pU, inv, W0, y, (float*)Bs);
}

// ---------------------------------------------------------------------------
extern "C" void kernel_launch(void* const* d_in, const int* in_sizes, int n_in,
                              void* d_out, int out_size, void* d_ws, size_t ws_size,
                              hipStream_t stream) {
  (void)in_sizes; (void)n_in; (void)out_size; (void)ws_size;
  const float* x0 = (const float*)d_in[0];
  const float* x1 = (const float*)d_in[1];
  const float* L0 = (const float*)d_in[3];
  const float* B1 = (const float*)d_in[8];
  const float* W0 = (const float*)d_in[10];

  float* ws = (float*)d_ws;
  int* bar = (int*)(ws + OFF_BAR);

  init_bar_kernel<<<1, 256, 0, stream>>>(bar);
  mega_kernel<<<1024, 256, 0, stream>>>(x0, x1, L0, B1, W0, ws, bar, (float*)d_out);
}

// Round 4
// 134.527 us; speedup vs baseline: 6.3265x; 6.3265x over previous
//
#include <hip/hip_runtime.h>
#include <hip/hip_bf16.h>
#include <math.h>

#define N0 4096
#define NM1 8192

// workspace float offsets
#define OFF_XL1 0
#define OFF_XL2 65536
#define OFF_UL1 131072
#define OFF_UL2 196608
#define OFF_INV 262144
#define OFF_PB  266240      // 4 * 65536 (b1 partials)
#define OFF_PX  528384      // 8 * 65536
#define OFF_PU  1052672     // 8 * 65536
#define OFF_PRS 1576960     // 8 * 4096

// butterfly reduce-scatter: 2*NV values -> NV, exchanging with lane^d
template<int NV>
__device__ __forceinline__ void red_scatter(float* v, const int d, const int lane) {
  const bool up = (lane & d) != 0;
  #pragma unroll
  for (int i = 0; i < NV; ++i) {
    float send = up ? v[i] : v[i + NV];
    float recv = __shfl_xor(send, d);
    float keep = up ? v[i + NV] : v[i];
    v[i] = keep + recv;
  }
}

// ---------------------------------------------------------------------------
// pB[s] = B1[rows, m-range(s)] @ x1   (round-2 proven kernel, verbatim)
// grid 1024 = 256 rg x 4 s; block 256 (4 waves, 4 rows/wave).
// ---------------------------------------------------------------------------
__global__ __launch_bounds__(256)
void b1_matmul_kernel(const float* __restrict__ A,   // [4096][8192]
                      const float* __restrict__ X,   // [8192][16]
                      float* __restrict__ pP)        // [4][4096][16]
{
  __shared__ float4 Bs[2048];                        // 32 KiB
  const int tid  = threadIdx.x;
  const int wv   = tid >> 6;
  const int lane = tid & 63;
  const int q    = lane >> 5;
  const int ml   = lane & 31;
  const int s    = blockIdx.x & 3;
  const int rg   = blockIdx.x >> 2;
  const int row0 = rg * 16 + wv * 4;

  float acc[32];
  #pragma unroll
  for (int i = 0; i < 32; ++i) acc[i] = 0.0f;
  const int j0 = q * 2;
  const int jj = tid & 3;
  const int mt = tid >> 2;

  for (int ch = 0; ch < 4; ++ch) {
    const int mb = s * 2048 + ch * 512;
    __syncthreads();
    #pragma unroll
    for (int k = 0; k < 8; ++k) {
      const int m = mt + 64 * k;
      Bs[(m * 4 + jj) ^ ((m >> 2) & 7)] =
          *(const float4*)(X + (size_t)(mb + m) * 16 + jj * 4);
    }
    __syncthreads();
    #pragma unroll
    for (int it = 0; it < 4; ++it) {
      const int mloc = it * 128 + ml * 4;
      float a[4][4];
      #pragma unroll
      for (int r = 0; r < 4; ++r) {
        const float4 t4 = *(const float4*)(A + (size_t)(row0 + r) * NM1 + mb + mloc);
        a[r][0] = t4.x; a[r][1] = t4.y; a[r][2] = t4.z; a[r][3] = t4.w;
      }
      #pragma unroll
      for (int v = 0; v < 4; ++v) {
        const int mm = mloc + v;
        const int h = (mm >> 2) & 7;
        const float4 b0  = Bs[(mm * 4 + j0) ^ h];
        const float4 b1v = Bs[(mm * 4 + j0 + 1) ^ h];
        #pragma unroll
        for (int r = 0; r < 4; ++r) {
          const float av = a[r][v];
          acc[r*8+0] += av * b0.x;   acc[r*8+1] += av * b0.y;
          acc[r*8+2] += av * b0.z;   acc[r*8+3] += av * b0.w;
          acc[r*8+4] += av * b1v.x;  acc[r*8+5] += av * b1v.y;
          acc[r*8+6] += av * b1v.z;  acc[r*8+7] += av * b1v.w;
        }
      }
    }
  }

  red_scatter<16>(acc, 1, lane);
  red_scatter<8>(acc, 2, lane);
  red_scatter<4>(acc, 4, lane);
  red_scatter<2>(acc, 8, lane);
  red_scatter<1>(acc, 16, lane);

  const int r = 2 * (ml & 1) + ((ml >> 1) & 1);
  const int c = 4 * ((ml >> 2) & 1) + 2 * ((ml >> 3) & 1) + ((ml >> 4) & 1);
  pP[(size_t)(s * N0 + row0 + r) * 16 + q * 8 + c] = acc[0];
}

// ---------------------------------------------------------------------------
// Cheb step partials, both chains (R=8 rows/wave geometry, proven in mega):
//   pX/pU[s] = L0[rows, m-range(s)] @ {cx, cu};  pRS[s] = rowsum when RS.
// grid 1024 = 128 rg x 8 s; block 256 (4 waves, 8 rows/wave).
// q=lane>>3 col-block (0-3 x-chain, 4-7 u-chain), ml=lane&7.
// When SUMU: u-half staging sums the 4 b1-partials from `cu` (=pB).
// ---------------------------------------------------------------------------
template<bool RS, bool SUMU>
__global__ __launch_bounds__(256)
void cheb_kernel(const float* __restrict__ A,    // [4096][4096]
                 const float* __restrict__ cx,   // [4096][16]
                 const float* __restrict__ cu,   // [4096][16] or pB[4][4096][16]
                 float* __restrict__ pX,         // [8][4096][16]
                 float* __restrict__ pU,         // [8][4096][16]
                 float* __restrict__ pRS)        // [8][4096]
{
  __shared__ float4 Bs[2048];                    // 256 m x 8 col-blocks, 32 KiB
  const int tid  = threadIdx.x;
  const int wv   = tid >> 6;
  const int lane = tid & 63;
  const int q    = lane >> 3;
  const int ml   = lane & 7;
  const int s    = blockIdx.x & 7;
  const int rg   = blockIdx.x >> 3;
  const int row0 = rg * 32 + wv * 8;
  const int mbase = s * 512;

  float acc[32];
  #pragma unroll
  for (int i = 0; i < 32; ++i) acc[i] = 0.0f;
  float rs[8] = {};

  const int jj = tid & 7;
  const int mt = tid >> 3;     // 0..31
  const float* sbase = (jj < 4) ? cx : cu;
  const int joff = (jj & 3) * 4;

  #pragma unroll 1
  for (int ch = 0; ch < 2; ++ch) {
    const int mb = mbase + ch * 256;
    __syncthreads();
    #pragma unroll
    for (int k = 0; k < 8; ++k) {
      const int m = mt + 32 * k;
      float4 val;
      if constexpr (SUMU) {
        if (jj >= 4) {
          const float* pb = cu + (size_t)(mb + m) * 16 + joff;
          const float4 t0 = *(const float4*)(pb);
          const float4 t1 = *(const float4*)(pb + 65536);
          const float4 t2 = *(const float4*)(pb + 131072);
          const float4 t3 = *(const float4*)(pb + 196608);
          val = make_float4(t0.x + t1.x + t2.x + t3.x,
                            t0.y + t1.y + t2.y + t3.y,
                            t0.z + t1.z + t2.z + t3.z,
                            t0.w + t1.w + t2.w + t3.w);
        } else {
          val = *(const float4*)(cx + (size_t)(mb + m) * 16 + joff);
        }
      } else {
        val = *(const float4*)(sbase + (size_t)(mb + m) * 16 + joff);
      }
      Bs[(m * 8 + jj) ^ ((m >> 2) & 7)] = val;
    }
    __syncthreads();
    #pragma unroll 2
    for (int it = 0; it < 8; ++it) {
      const int mloc = it * 32 + ml * 4;
      float a_[8][4];
      #pragma unroll
      for (int r = 0; r < 8; ++r) {
        const float4 t4 = *(const float4*)(A + (size_t)(row0 + r) * N0 + mb + mloc);
        a_[r][0] = t4.x; a_[r][1] = t4.y; a_[r][2] = t4.z; a_[r][3] = t4.w;
      }
      #pragma unroll
      for (int v = 0; v < 4; ++v) {
        const int mm = mloc + v;
        const float4 b0 = Bs[(mm * 8 + q) ^ ((mm >> 2) & 7)];
        #pragma unroll
        for (int r = 0; r < 8; ++r) {
          const float av = a_[r][v];
          acc[r*4+0] += av * b0.x;  acc[r*4+1] += av * b0.y;
          acc[r*4+2] += av * b0.z;  acc[r*4+3] += av * b0.w;
          if constexpr (RS) rs[r] += av;
        }
      }
    }
  }

  // reduce across 8 m-lanes: 32 vals -> 4 per lane
  red_scatter<16>(acc, 1, lane);
  red_scatter<8>(acc, 2, lane);
  red_scatter<4>(acc, 4, lane);

  const int r = 4 * (ml & 1) + 2 * ((ml >> 1) & 1) + ((ml >> 2) & 1);
  float* base = (q >> 2) ? pU : pX;
  *(float4*)(base + (size_t)(s * 65536) + (row0 + r) * 16 + (q & 3) * 4) =
      make_float4(acc[0], acc[1], acc[2], acc[3]);

  if constexpr (RS) {
    red_scatter<4>(rs, 1, lane);
    red_scatter<2>(rs, 2, lane);
    red_scatter<1>(rs, 4, lane);
    if (q == 0) pRS[s * N0 + row0 + r] = rs[0];
  }
}

// ---------------------------------------------------------------------------
// norm1: inv = 1/sum8(pRS) (nonfinite->0); normalize step-1 partials.
// ---------------------------------------------------------------------------
__global__ void norm1_kernel(const float* __restrict__ pX,
                             const float* __restrict__ pU,
                             const float* __restrict__ pRS,
                             float* __restrict__ inv,
                             float* __restrict__ ox,
                             float* __restrict__ ou) {
  const int idx = blockIdx.x * 256 + threadIdx.x;   // < 65536
  const int row = idx >> 4;
  float rsv = 0.0f;
  #pragma unroll
  for (int s2 = 0; s2 < 8; ++s2) rsv += pRS[s2 * N0 + row];
  float iv = 1.0f / rsv;
  if (!isfinite(iv)) iv = 0.0f;
  if ((idx & 15) == 0) inv[row] = iv;
  float xv = 0.0f, uv = 0.0f;
  #pragma unroll
  for (int s2 = 0; s2 < 8; ++s2) { xv += pX[s2*65536 + idx]; uv += pU[s2*65536 + idx]; }
  xv *= iv; uv *= iv;
  ox[idx] = isfinite(xv) ? xv : 0.0f;
  ou[idx] = isfinite(uv) ? uv : 0.0f;
}

__global__ void norm23_kernel(const float* __restrict__ pX,
                              const float* __restrict__ pU,
                              const float* __restrict__ inv,
                              float* __restrict__ ox,
                              float* __restrict__ ou) {
  const int idx = blockIdx.x * 256 + threadIdx.x;   // < 65536
  const float iv = inv[idx >> 4];
  float xv = 0.0f, uv = 0.0f;
  #pragma unroll
  for (int s2 = 0; s2 < 8; ++s2) { xv += pX[s2*65536 + idx]; uv += pU[s2*65536 + idx]; }
  xv *= iv; uv *= iv;
  ox[idx] = isfinite(xv) ? xv : 0.0f;
  ou[idx] = isfinite(uv) ? uv : 0.0f;
}

// ---------------------------------------------------------------------------
// y0[n,o] = sum_{i,k} xall[n,i,k]*W[i,o,k]; k: 0=x0, 1..3=xlap, 4=u, 5..7=ulap.
// k=3,7 (step-3 norm) fused from pX/pU partials; k=4 (u) summed from pB.
// ---------------------------------------------------------------------------
__global__ void einsum_kernel(const float* __restrict__ x0,
                              const float* __restrict__ xl1,
                              const float* __restrict__ xl2,
                              const float* __restrict__ pB,
                              const float* __restrict__ ul1,
                              const float* __restrict__ ul2,
                              const float* __restrict__ pX,
                              const float* __restrict__ pU,
                              const float* __restrict__ inv,
                              const float* __restrict__ W,   // [16][16][8]
                              float* __restrict__ y) {
  __shared__ float Wl[2048];
  __shared__ float xs[16 * 128];                 // [r][k][i]
  const int t = threadIdx.x;
  const int row0 = blockIdx.x * 16;
  #pragma unroll
  for (int k = 0; k < 8; ++k) Wl[t + 256 * k] = W[t + 256 * k];
  const int r = t >> 4;
  const int i = t & 15;
  const int g = (row0 + r) * 16 + i;
  const float iv = inv[row0 + r];
  float x3 = 0.0f, u3 = 0.0f;
  #pragma unroll
  for (int s2 = 0; s2 < 8; ++s2) { x3 += pX[s2*65536 + g]; u3 += pU[s2*65536 + g]; }
  x3 *= iv; u3 *= iv;
  if (!isfinite(x3)) x3 = 0.0f;
  if (!isfinite(u3)) u3 = 0.0f;
  const float uval = pB[g] + pB[65536 + g] + pB[131072 + g] + pB[196608 + g];
  xs[r*128 + 0*16 + i] = x0[g];
  xs[r*128 + 1*16 + i] = xl1[g];
  xs[r*128 + 2*16 + i] = xl2[g];
  xs[r*128 + 3*16 + i] = x3;
  xs[r*128 + 4*16 + i] = uval;
  xs[r*128 + 5*16 + i] = ul1[g];
  xs[r*128 + 6*16 + i] = ul2[g];
  xs[r*128 + 7*16 + i] = u3;
  __syncthreads();
  const int o = t & 15;
  float a = 0.0f;
  #pragma unroll
  for (int ii = 0; ii < 16; ++ii) {
    #pragma unroll
    for (int k = 0; k < 8; ++k)
      a += xs[r*128 + k*16 + ii] * Wl[(ii*16 + o)*8 + k];
  }
  y[(row0 + r) * 16 + o] = a;
}

// ---------------------------------------------------------------------------
extern "C" void kernel_launch(void* const* d_in, const int* in_sizes, int n_in,
                              void* d_out, int out_size, void* d_ws, size_t ws_size,
                              hipStream_t stream) {
  (void)in_sizes; (void)n_in; (void)out_size; (void)ws_size;
  const float* x0 = (const float*)d_in[0];
  const float* x1 = (const float*)d_in[1];
  const float* L0 = (const float*)d_in[3];
  const float* B1 = (const float*)d_in[8];
  const float* W0 = (const float*)d_in[10];

  float* ws  = (float*)d_ws;
  float* xl1 = ws + OFF_XL1;
  float* xl2 = ws + OFF_XL2;
  float* ul1 = ws + OFF_UL1;
  float* ul2 = ws + OFF_UL2;
  float* inv = ws + OFF_INV;
  float* pB  = ws + OFF_PB;
  float* pX  = ws + OFF_PX;
  float* pU  = ws + OFF_PU;
  float* pRS = ws + OFF_PRS;

  // u-partials = b1 @ x_1   (finalize fused into cheb1 staging + einsum)
  b1_matmul_kernel<<<1024, 256, 0, stream>>>(B1, x1, pB);

  // step 1: stages u from pB (SUMU), computes rowsum
  cheb_kernel<true, true><<<1024, 256, 0, stream>>>(L0, x0, pB, pX, pU, pRS);
  norm1_kernel<<<256, 256, 0, stream>>>(pX, pU, pRS, inv, xl1, ul1);
  // step 2
  cheb_kernel<false, false><<<1024, 256, 0, stream>>>(L0, xl1, ul1, pX, pU, pRS);
  norm23_kernel<<<256, 256, 0, stream>>>(pX, pU, inv, xl2, ul2);
  // step 3 (normalization fused into einsum)
  cheb_kernel<false, false><<<1024, 256, 0, stream>>>(L0, xl2, ul2, pX, pU, pRS);

  // y_0 = einsum('nik,iok->no', x_0_all, weight_0)
  einsum_kernel<<<256, 256, 0, stream>>>(x0, xl1, xl2, pB, ul1, ul2,
                                         pX, pU, inv, W0, (float*)d_out);
}